// Round 12
// baseline (619.889 us; speedup 1.0000x reference)
//
#include <hip/hip_runtime.h>
#include <hip/hip_bf16.h>
#include <stdint.h>

// Problem constants: B=8,S=1024,D=1024,E=8,H=4096,top_k=2
#define TKN   8192
#define DD    1024
#define EE    8
#define HH    4096
#define TOPK  2
#define NASG  (TKN * TOPK)      // 16384 assignments
#define NSLOT 136               // sum_e ceil(cnt_e/128) <= 128+8
#define SLOTX 17                // slots per XCD (8*17 = 136)

typedef unsigned short u16;
typedef __bf16 bf16x8 __attribute__((ext_vector_type(8)));
typedef float  f32x4  __attribute__((ext_vector_type(4)));

__device__ __forceinline__ u16 f2bf(float f) {
  __hip_bfloat16 h = __float2bfloat16(f);
  return __builtin_bit_cast(u16, h);
}
__device__ __forceinline__ float bf2f(u16 u) {
  uint32_t v = ((uint32_t)u) << 16;
  return __builtin_bit_cast(float, v);
}

__device__ __forceinline__ void glds16(const void* g, void* l) {
  __builtin_amdgcn_global_load_lds(
      (__attribute__((address_space(1))) void*)g,
      (__attribute__((address_space(3))) void*)l, 16, 0, 0);
}

#define FENCE() asm volatile("" ::: "memory")
#define BAR()   do { FENCE(); __builtin_amdgcn_s_barrier(); FENCE(); } while (0)
#define VMCNT0() asm volatile("s_waitcnt vmcnt(0)" ::: "memory")

// ---------------- transpose + f32->bf16: [E][R][C] f32 -> [E][C][R] bf16
__global__ __launch_bounds__(256) void transpose_cvt_kernel(
    const float* __restrict__ src, u16* __restrict__ dst, int R, int C) {
  __shared__ float tile[64][33];
  int e = blockIdx.z;
  int c0 = blockIdx.x * 32, r0 = blockIdx.y * 64;
  int tx = threadIdx.x, ty = threadIdx.y;  // 32 x 8
  const float* s = src + (size_t)e * R * C;
  uint32_t* d32 = (uint32_t*)(dst + (size_t)e * R * C);
#pragma unroll
  for (int j = 0; j < 8; j++)
    tile[ty * 8 + j][tx] = s[(size_t)(r0 + ty * 8 + j) * C + c0 + tx];
  __syncthreads();
#pragma unroll
  for (int jj = 0; jj < 4; jj++) {
    int c = c0 + ty * 4 + jj;
    uint32_t lo = f2bf(tile[2 * tx][ty * 4 + jj]);
    uint32_t hi = f2bf(tile[2 * tx + 1][ty * 4 + jj]);
    d32[((size_t)c * R + r0) / 2 + tx] = lo | (hi << 16);
  }
}

// ---------------- router (writes the FULL 8-wide gating row; no memset needed)
__global__ __launch_bounds__(256) void router_kernel(
    const float* __restrict__ x, const float* __restrict__ noise,
    const float* __restrict__ Wg, const float* __restrict__ bg,
    const float* __restrict__ Wn, const float* __restrict__ bn,
    float* __restrict__ gating, u16* __restrict__ xb,
    int* __restrict__ sel_e, float* __restrict__ sel_g) {
  int t = blockIdx.x;
  int tid = threadIdx.x;
  float acc[16];
#pragma unroll
  for (int j = 0; j < 16; j++) acc[j] = 0.f;
  for (int i = tid; i < DD; i += 256) {
    float xv = x[(size_t)t * DD + i];
    xb[(size_t)t * DD + i] = f2bf(xv);
    const float4* g4 = (const float4*)(Wg + (size_t)i * EE);
    const float4* n4 = (const float4*)(Wn + (size_t)i * EE);
    float4 ga = g4[0], gb = g4[1];
    float4 na = n4[0], nb = n4[1];
    acc[0] += xv * ga.x;  acc[1] += xv * ga.y;  acc[2] += xv * ga.z;  acc[3] += xv * ga.w;
    acc[4] += xv * gb.x;  acc[5] += xv * gb.y;  acc[6] += xv * gb.z;  acc[7] += xv * gb.w;
    acc[8] += xv * na.x;  acc[9] += xv * na.y;  acc[10] += xv * na.z; acc[11] += xv * na.w;
    acc[12] += xv * nb.x; acc[13] += xv * nb.y; acc[14] += xv * nb.z; acc[15] += xv * nb.w;
  }
  __shared__ float red[4][16];
  int lane = tid & 63, wv = tid >> 6;
#pragma unroll
  for (int j = 0; j < 16; j++) {
    float v = acc[j];
    for (int o = 32; o > 0; o >>= 1) v += __shfl_down(v, o);
    acc[j] = v;
  }
  if (lane == 0) {
#pragma unroll
    for (int j = 0; j < 16; j++) red[wv][j] = acc[j];
  }
  __syncthreads();
  if (tid == 0) {
    float nz[EE];
#pragma unroll
    for (int e = 0; e < EE; e++) {
      float dg = red[0][e] + red[1][e] + red[2][e] + red[3][e] + bg[e];
      float dn = red[0][8 + e] + red[1][8 + e] + red[2][8 + e] + red[3][8 + e] + bn[e];
      float sp = fmaxf(dn, 0.f) + log1pf(expf(-fabsf(dn)));
      nz[e] = dg + noise[(size_t)t * EE + e] * sp;
    }
    int m1 = 0;
    for (int e = 1; e < EE; e++) if (nz[e] > nz[m1]) m1 = e;
    int m2 = (m1 == 0) ? 1 : 0;
    for (int e = 0; e < EE; e++) if (e != m1 && nz[e] > nz[m2]) m2 = e;
    float eb = expf(nz[m2] - nz[m1]);
    float den = 1.f + eb;
    float g1 = 1.f / den, g2 = eb / den;
#pragma unroll
    for (int e = 0; e < EE; e++)
      gating[(size_t)t * EE + e] = (e == m1) ? g1 : (e == m2) ? g2 : 0.f;
    sel_e[t * 2] = m1; sel_e[t * 2 + 1] = m2;
    sel_g[t * 2] = g1; sel_g[t * 2 + 1] = g2;
  }
}

// ---------------- histogram + scan + slot table (1 block); 128-row tiles
__global__ __launch_bounds__(256) void hist_scan_kernel(
    const int* __restrict__ sel_e, int* __restrict__ counts,
    int* __restrict__ offsets, int* __restrict__ cursors,
    int* __restrict__ slots) {
  __shared__ int hist[EE];
  int tid = threadIdx.x;
  if (tid < EE) hist[tid] = 0;
  __syncthreads();
  for (int i = tid; i < NASG; i += 256) atomicAdd(&hist[sel_e[i]], 1);
  __syncthreads();
  if (tid == 0) {
    int off = 0, ns = 0;
    for (int e = 0; e < EE; e++) {
      int c = hist[e];
      counts[e] = c; offsets[e] = off; cursors[e] = off; off += c;
      int nrt = (c + 127) >> 7;
      for (int rt = 0; rt < nrt; rt++) slots[ns++] = (e << 16) | rt;
    }
    for (; ns < NSLOT; ns++) slots[ns] = -1;
  }
}

// ---------------- build per-expert token lists (+ token->assignment-slot map)
__global__ __launch_bounds__(256) void build_lists_kernel(
    const int* __restrict__ sel_e, const float* __restrict__ sel_g,
    int* __restrict__ cursors, int* __restrict__ tok_list,
    float* __restrict__ gate_list, int* __restrict__ asg_of) {
  int t = blockIdx.x * 256 + threadIdx.x;
  int lane = threadIdx.x & 63;
#pragma unroll
  for (int k = 0; k < TOPK; k++) {
    int e = sel_e[t * 2 + k];
    float g = sel_g[t * 2 + k];
    for (int ee = 0; ee < EE; ee++) {
      unsigned long long m = __ballot(e == ee);
      if (m) {
        int leader = __ffsll(m) - 1;
        int base = 0;
        if (lane == leader) base = atomicAdd(&cursors[ee], __popcll(m));
        base = __shfl(base, leader);
        if (e == ee) {
          int slot = base + __popcll(m & ((1ull << lane) - 1ull));
          tok_list[slot] = t;
          gate_list[slot] = g;
          asg_of[t * 2 + k] = slot;
        }
      }
    }
  }
}

// ---------------- zero-fill non-selected expert_out rows (fallback path only)
__global__ __launch_bounds__(256) void zerofill_kernel(
    const float* __restrict__ gating, float* __restrict__ expert_out) {
  int id = blockIdx.x;              // 0 .. EE*TKN-1
  int e = id >> 13, t = id & (TKN - 1);
  if (gating[(size_t)t * EE + e] != 0.f) return;
  float4* p = (float4*)(expert_out + ((size_t)e * TKN + t) * DD);
  p[threadIdx.x] = (float4){0.f, 0.f, 0.f, 0.f};
}

// ---------------- combine (fallback path): final = expert rows sum
__global__ __launch_bounds__(256) void combine_kernel(
    const float* __restrict__ expert_out, const int* __restrict__ sel_e,
    float* __restrict__ final_out) {
  int t = blockIdx.x;
  int e1 = sel_e[2 * t], e2 = sel_e[2 * t + 1];
  const float4* r1 = (const float4*)(expert_out + ((size_t)e1 * TKN + t) * DD);
  const float4* r2 = (const float4*)(expert_out + ((size_t)e2 * TKN + t) * DD);
  float4* o = (float4*)(final_out + (size_t)t * DD);
  int i = threadIdx.x;
  float4 a = r1[i], b = r2[i];
  o[i] = (float4){a.x + b.x, a.y + b.y, a.z + b.z, a.w + b.w};
}

// ---------------- finalize: merge 4 bf16 K-partials + bias + gate, write ALL
// 8 expert rows per token (zeros for non-selected) + final.
__global__ __launch_bounds__(256) void finalize_kernel(
    const u16* __restrict__ part, const int* __restrict__ asg_of,
    const int* __restrict__ sel_e, const float* __restrict__ sel_g,
    const float* __restrict__ b2, float* __restrict__ expert_out,
    float* __restrict__ final_out) {
  int t = blockIdx.x;
  int i = threadIdx.x;
  int i1 = asg_of[2 * t], i2 = asg_of[2 * t + 1];
  int e1 = sel_e[2 * t], e2 = sel_e[2 * t + 1];
  float g1 = sel_g[2 * t], g2 = sel_g[2 * t + 1];
  float s1[4] = {0.f, 0.f, 0.f, 0.f}, s2[4] = {0.f, 0.f, 0.f, 0.f};
#pragma unroll
  for (int kq = 0; kq < 4; kq++) {
    ushort4 a = ((const ushort4*)(part + ((size_t)kq * NASG + i1) * DD))[i];
    ushort4 b = ((const ushort4*)(part + ((size_t)kq * NASG + i2) * DD))[i];
    s1[0] += bf2f(a.x); s1[1] += bf2f(a.y); s1[2] += bf2f(a.z); s1[3] += bf2f(a.w);
    s2[0] += bf2f(b.x); s2[1] += bf2f(b.y); s2[2] += bf2f(b.z); s2[3] += bf2f(b.w);
  }
  float4 bb1 = ((const float4*)(b2 + (size_t)e1 * DD))[i];
  float4 bb2 = ((const float4*)(b2 + (size_t)e2 * DD))[i];
  float4 y1 = {(s1[0] + bb1.x) * g1, (s1[1] + bb1.y) * g1,
               (s1[2] + bb1.z) * g1, (s1[3] + bb1.w) * g1};
  float4 y2 = {(s2[0] + bb2.x) * g2, (s2[1] + bb2.y) * g2,
               (s2[2] + bb2.z) * g2, (s2[3] + bb2.w) * g2};
  float4 z = {0.f, 0.f, 0.f, 0.f};
#pragma unroll
  for (int e = 0; e < EE; e++) {
    float4 v = (e == e1) ? y1 : (e == e2) ? y2 : z;
    ((float4*)(expert_out + ((size_t)e * TKN + t) * DD))[i] = v;
  }
  ((float4*)(final_out + (size_t)t * DD))[i] =
      (float4){y1.x + y2.x, y1.y + y2.y, y1.z + y2.z, y1.w + y2.w};
}

// ---------------- 128x256 / BK=32 / 4-wave grouped GEMM, 2 blocks/CU.
// Rationale: 4 schedule variants at the 256²/8-wave/1-block-per-CU shape all
// pinned at ~5500 cyc/tile — with one block per CU the barrier phase-locks
// the whole CU and LDS-read + MFMA serialize. m97/m114: the overlap comes
// from INTER-BLOCK TLP. This shape keeps the identical per-wave budget
// (acc 8x4 = 128 AGPR + ~110 VGPR, 2 waves/SIMD) but packs it into 4-wave
// blocks with 48 KB LDS -> 2 blocks co-resident per CU; the co-resident
// block's ds_reads fill this block's MFMA windows and vice versa.
// Per tile per wave: issue glds(t+1) [depth-1, parity (t+1)&1]; 12x
// ds_read_b128 (aF[8], bF[4]); 32 MFMA (no intra-tile acc chains);
// vmcnt(0); barrier.  WAR/RAW ledger identical to round 9 (verified):
// glds(t+1) overwrites the buffer whose reads completed before the t-1
// barrier; reads of buf(t) gated by own vmcnt(0) + barrier at end of t-1.
// LDS swizzle (verified round 4): row = 32 bf16 = 4 chunks of 16B; stored
// chunk c of row r holds global chunk c^((r>>1)&3). Staging pre-applies the
// involution on the GLOBAL per-lane address (gch), LDS dest stays linear;
// reads use koff = (hi ^ ((fr>>1)&3))<<4 (fragment rows = 16m+fr keep bits
// 1-2 of fr).  2-way bank aliasing only (free tier).
// Decode (1-D grid, kq-outer within XCD): gid -> xcd=gid&7, q=gid>>3,
// kq=q/(SLOTX<<LOGC), r=q%(..), slot=xcd*SLOTX+(r>>LOGC), ct=r&mask.
// EPI: 0 = relu->bf16 OutBf; 1 = (acc+bias)*gate -> f32 outF; 2 = bf16
// K-partial -> outP[kq][asg][DD].
template<int KLOOP, int KSTRIDE, bool GATHER, int EPI, int LOGC>
__global__ __launch_bounds__(256, 2) void gemm4_kernel(
    const u16* __restrict__ A, const u16* __restrict__ Bm,
    const float* __restrict__ bias, const int* __restrict__ tok_list,
    const float* __restrict__ gate_list, const int* __restrict__ counts,
    const int* __restrict__ offsets, const int* __restrict__ slots,
    int Ncols, u16* __restrict__ OutBf, float* __restrict__ outF,
    u16* __restrict__ outP) {
  constexpr int NT = KLOOP / 32;
  int gid = blockIdx.x;
  int q = gid >> 3;
  constexpr int PERX = SLOTX << LOGC;
  int kq = q / PERX;
  int r0q = q - kq * PERX;
  int slot = (gid & 7) * SLOTX + (r0q >> LOGC);
  int ct = r0q & ((1 << LOGC) - 1);
  int packed = slots[slot];
  if (packed < 0) return;
  int e = packed >> 16;
  int rt = packed & 0xffff;
  int cnt = counts[e];
  int off = offsets[e];
  int col0 = ct * 256;
  int k0e = kq * KLOOP;

  __shared__ __attribute__((aligned(16))) char ldsc[49152];  // 2 x (A 8K | B 16K)

  int tid = threadIdx.x;
  int w = tid >> 6, l = tid & 63;
  int wn = w;                       // 4 waves across N (64 cols each)
  int fr = l & 15, hi = l >> 4;
  int koff = (hi ^ ((fr >> 1) & 3)) << 4;

  int rowL = tid >> 2;              // 0..63
  int gch = (tid & 3) ^ ((rowL >> 1) & 3);
  const u16* aptr[2];
  const u16* bptr[4];
#pragma unroll
  for (int i = 0; i < 2; i++) {
    int r = rt * 128 + i * 64 + rowL;
    if (GATHER) {
      int idx = min(off + r, NASG - 1);
      aptr[i] = A + (size_t)tok_list[idx] * KSTRIDE + k0e + gch * 8;
    } else {
      aptr[i] = A + (size_t)(off + r) * KSTRIDE + k0e + gch * 8;
    }
  }
#pragma unroll
  for (int i = 0; i < 4; i++)
    bptr[i] = Bm + ((size_t)e * Ncols + col0 + i * 64 + rowL) * KSTRIDE + k0e + gch * 8;

  auto issueAB = [&](int t) {
    char* base = ldsc + (t & 1) * 24576;
    char* da = base + w * 1024;
    glds16(aptr[0] + t * 32, da);
    glds16(aptr[1] + t * 32, da + 4096);
    char* db = base + 8192 + w * 1024;
    glds16(bptr[0] + t * 32, db);
    glds16(bptr[1] + t * 32, db + 4096);
    glds16(bptr[2] + t * 32, db + 8192);
    glds16(bptr[3] + t * 32, db + 12288);
  };

  f32x4 acc[8][4];
#pragma unroll
  for (int m = 0; m < 8; m++)
#pragma unroll
    for (int n = 0; n < 4; n++) acc[m][n] = (f32x4){0.f, 0.f, 0.f, 0.f};
  bf16x8 aF[8], bF[4];

  // prologue: stage tile 0; drain; barrier
  issueAB(0);
  VMCNT0();
  BAR();

  for (int t = 0; t < NT; t++) {
    int ab = (t & 1) * 24576;
    int bb = ab + 8192;
    if (t + 1 < NT) issueAB(t + 1);   // depth-1 prefetch, parity (t+1)&1
#pragma unroll
    for (int m = 0; m < 8; m++)
      aF[m] = *(const bf16x8*)(ldsc + ab + (m * 16 + fr) * 64 + koff);
#pragma unroll
    for (int n = 0; n < 4; n++)
      bF[n] = *(const bf16x8*)(ldsc + bb + (wn * 64 + n * 16 + fr) * 64 + koff);
    __builtin_amdgcn_s_setprio(1);
#pragma unroll
    for (int m = 0; m < 8; m++)
#pragma unroll
      for (int n = 0; n < 4; n++)
        acc[m][n] = __builtin_amdgcn_mfma_f32_16x16x32_bf16(aF[m], bF[n], acc[m][n], 0, 0, 0);
    __builtin_amdgcn_s_setprio(0);
    VMCNT0();   // own glds(t+1) done (issued a full tile ago)
    BAR();      // everyone's done; buf(t) free for glds(t+2)
  }

  // ---- epilogue
  float biasN[4];
  int cN[4];
#pragma unroll
  for (int n = 0; n < 4; n++) {
    cN[n] = col0 + wn * 64 + n * 16 + fr;
    biasN[n] = (EPI == 2) ? 0.f : bias[e * Ncols + cN[n]];
  }
  if constexpr (EPI == 0) {
#pragma unroll
    for (int m = 0; m < 8; m++) {
      int rb = rt * 128 + m * 16 + hi * 4;
#pragma unroll
      for (int j = 0; j < 4; j++) {
        int r = rb + j;
        if (r < cnt) {
#pragma unroll
          for (int n = 0; n < 4; n++) {
            float v = acc[m][n][j] + biasN[n];
            OutBf[(size_t)(off + r) * Ncols + cN[n]] = f2bf(fmaxf(v, 0.f));
          }
        }
      }
    }
  } else if constexpr (EPI == 1) {
#pragma unroll
    for (int m = 0; m < 8; m++) {
      int rb = rt * 128 + m * 16 + hi * 4;
#pragma unroll
      for (int j = 0; j < 4; j++) {
        int r = rb + j;
        if (r < cnt) {
          int idx = off + r;
          int tok = tok_list[idx];
          float g = gate_list[idx];
          size_t erow = ((size_t)e * TKN + tok) * DD;
#pragma unroll
          for (int n = 0; n < 4; n++)
            outF[erow + cN[n]] = (acc[m][n][j] + biasN[n]) * g;
        }
      }
    }
  } else {
    // bf16 K-partial: outP[kq][asg][DD]
#pragma unroll
    for (int m = 0; m < 8; m++) {
      int rb = rt * 128 + m * 16 + hi * 4;
#pragma unroll
      for (int j = 0; j < 4; j++) {
        int r = rb + j;
        if (r < cnt) {
          size_t prow = ((size_t)kq * NASG + off + r) * DD;
#pragma unroll
          for (int n = 0; n < 4; n++)
            outP[prow + cN[n]] = f2bf(acc[m][n][j]);
        }
      }
    }
  }
}

extern "C" void kernel_launch(void* const* d_in, const int* in_sizes, int n_in,
                              void* d_out, int out_size, void* d_ws, size_t ws_size,
                              hipStream_t stream) {
  const float* x     = (const float*)d_in[0];
  const float* noise = (const float*)d_in[1];
  const float* Wg    = (const float*)d_in[2];
  const float* bg    = (const float*)d_in[3];
  const float* Wn    = (const float*)d_in[4];
  const float* bn    = (const float*)d_in[5];
  const float* W1    = (const float*)d_in[6];
  const float* b1    = (const float*)d_in[7];
  const float* W2    = (const float*)d_in[8];
  const float* b2    = (const float*)d_in[9];

  float* final_out  = (float*)d_out;
  float* expert_out = final_out + (size_t)TKN * DD;
  float* gating     = expert_out + (size_t)EE * TKN * DD;

  char* ws = (char*)d_ws;
  size_t o = 0;
  auto alloc = [&](size_t bytes) {
    char* p = ws + o;
    o += bytes;
    o = (o + 255) & ~(size_t)255;
    return p;
  };
  u16*   xb        = (u16*)alloc((size_t)TKN * DD * 2);
  u16*   w1t       = (u16*)alloc((size_t)EE * HH * DD * 2);        // [E][H][D]
  u16*   w2t       = (u16*)alloc((size_t)EE * DD * HH * 2);        // [E][D][H]
  u16*   hbuf      = (u16*)alloc(((size_t)NASG + 256) * HH * 2);   // +256 pad rows
  int*   tok_list  = (int*)alloc((size_t)NASG * 4);
  float* gate_list = (float*)alloc((size_t)NASG * 4);
  int*   sel_e     = (int*)alloc((size_t)NASG * 4);
  float* sel_g     = (float*)alloc((size_t)NASG * 4);
  int*   asg_of    = (int*)alloc((size_t)NASG * 4);
  int*   counts    = (int*)alloc(256);
  int*   offsets   = (int*)alloc(256);
  int*   cursors   = (int*)alloc(256);
  int*   slots     = (int*)alloc(NSLOT * 4);
  u16*   part      = (u16*)alloc((size_t)4 * NASG * DD * 2);       // 134 MB (last)
  bool use_split = (o <= ws_size);

  router_kernel<<<TKN, 256, 0, stream>>>(x, noise, Wg, bg, Wn, bn, gating, xb, sel_e, sel_g);
  hist_scan_kernel<<<1, 256, 0, stream>>>(sel_e, counts, offsets, cursors, slots);
  build_lists_kernel<<<TKN / 256, 256, 0, stream>>>(sel_e, sel_g, cursors, tok_list,
                                                    gate_list, asg_of);

  transpose_cvt_kernel<<<dim3(HH / 32, DD / 64, EE), dim3(32, 8), 0, stream>>>(W1, w1t, DD, HH);
  transpose_cvt_kernel<<<dim3(DD / 32, HH / 64, EE), dim3(32, 8), 0, stream>>>(W2, w2t, HH, DD);

  // GEMM1: h = relu(x[tok] @ W1[e] + b1), K=1024, N=4096; 16 col-tiles of 256
  gemm4_kernel<DD, DD, true, 0, 4><<<8 * (SLOTX << 4), 256, 0, stream>>>(
      xb, w1t, b1, tok_list, nullptr, counts, offsets, slots, HH, hbuf, nullptr, nullptr);

  if (use_split) {
    // GEMM2 split-K x4: bf16 partials, then fused finalize (merge + zeros + final)
    gemm4_kernel<HH / 4, HH, false, 2, 2><<<8 * (SLOTX << 2) * 4, 256, 0, stream>>>(
        hbuf, w2t, b2, tok_list, gate_list, counts, offsets, slots, DD, nullptr, nullptr, part);
    finalize_kernel<<<TKN, 256, 0, stream>>>(part, asg_of, sel_e, sel_g, b2,
                                             expert_out, final_out);
  } else {
    // fallback: single-shot GEMM2 + zerofill + combine
    zerofill_kernel<<<EE * TKN, 256, 0, stream>>>(gating, expert_out);
    gemm4_kernel<HH, HH, false, 1, 2><<<8 * (SLOTX << 2), 256, 0, stream>>>(
        hbuf, w2t, b2, tok_list, gate_list, counts, offsets, slots, DD, nullptr, expert_out, nullptr);
    combine_kernel<<<TKN, 256, 0, stream>>>(expert_out, sel_e, final_out);
  }
}

// Round 13
// 600.803 us; speedup vs baseline: 1.0318x; 1.0318x over previous
//
#include <hip/hip_runtime.h>
#include <hip/hip_bf16.h>
#include <stdint.h>

// Problem constants: B=8,S=1024,D=1024,E=8,H=4096,top_k=2
#define TKN   8192
#define DD    1024
#define EE    8
#define HH    4096
#define TOPK  2
#define NASG  (TKN * TOPK)      // 16384 assignments
#define NSLOT 72                // >= sum_e ceil(cnt_e/256) (<= 64+7)

typedef unsigned short u16;
typedef __bf16 bf16x8 __attribute__((ext_vector_type(8)));
typedef float  f32x4  __attribute__((ext_vector_type(4)));

__device__ __forceinline__ u16 f2bf(float f) {
  __hip_bfloat16 h = __float2bfloat16(f);
  return __builtin_bit_cast(u16, h);
}
__device__ __forceinline__ float bf2f(u16 u) {
  uint32_t v = ((uint32_t)u) << 16;
  return __builtin_bit_cast(float, v);
}

__device__ __forceinline__ void glds16(const void* g, void* l) {
  __builtin_amdgcn_global_load_lds(
      (__attribute__((address_space(1))) void*)g,
      (__attribute__((address_space(3))) void*)l, 16, 0, 0);
}

#define FENCE() asm volatile("" ::: "memory")
#define BAR()   do { FENCE(); __builtin_amdgcn_s_barrier(); FENCE(); } while (0)
#define VMCNT0() asm volatile("s_waitcnt vmcnt(0)" ::: "memory")

// ---------------- transpose + f32->bf16: [E][R][C] f32 -> [E][C][R] bf16
__global__ __launch_bounds__(256) void transpose_cvt_kernel(
    const float* __restrict__ src, u16* __restrict__ dst, int R, int C) {
  __shared__ float tile[64][33];
  int e = blockIdx.z;
  int c0 = blockIdx.x * 32, r0 = blockIdx.y * 64;
  int tx = threadIdx.x, ty = threadIdx.y;  // 32 x 8
  const float* s = src + (size_t)e * R * C;
  uint32_t* d32 = (uint32_t*)(dst + (size_t)e * R * C);
#pragma unroll
  for (int j = 0; j < 8; j++)
    tile[ty * 8 + j][tx] = s[(size_t)(r0 + ty * 8 + j) * C + c0 + tx];
  __syncthreads();
#pragma unroll
  for (int jj = 0; jj < 4; jj++) {
    int c = c0 + ty * 4 + jj;
    uint32_t lo = f2bf(tile[2 * tx][ty * 4 + jj]);
    uint32_t hi = f2bf(tile[2 * tx + 1][ty * 4 + jj]);
    d32[((size_t)c * R + r0) / 2 + tx] = lo | (hi << 16);
  }
}

// ---------------- router (writes the FULL 8-wide gating row; no memset needed)
__global__ __launch_bounds__(256) void router_kernel(
    const float* __restrict__ x, const float* __restrict__ noise,
    const float* __restrict__ Wg, const float* __restrict__ bg,
    const float* __restrict__ Wn, const float* __restrict__ bn,
    float* __restrict__ gating, u16* __restrict__ xb,
    int* __restrict__ sel_e, float* __restrict__ sel_g) {
  int t = blockIdx.x;
  int tid = threadIdx.x;
  float acc[16];
#pragma unroll
  for (int j = 0; j < 16; j++) acc[j] = 0.f;
  for (int i = tid; i < DD; i += 256) {
    float xv = x[(size_t)t * DD + i];
    xb[(size_t)t * DD + i] = f2bf(xv);
    const float4* g4 = (const float4*)(Wg + (size_t)i * EE);
    const float4* n4 = (const float4*)(Wn + (size_t)i * EE);
    float4 ga = g4[0], gb = g4[1];
    float4 na = n4[0], nb = n4[1];
    acc[0] += xv * ga.x;  acc[1] += xv * ga.y;  acc[2] += xv * ga.z;  acc[3] += xv * ga.w;
    acc[4] += xv * gb.x;  acc[5] += xv * gb.y;  acc[6] += xv * gb.z;  acc[7] += xv * gb.w;
    acc[8] += xv * na.x;  acc[9] += xv * na.y;  acc[10] += xv * na.z; acc[11] += xv * na.w;
    acc[12] += xv * nb.x; acc[13] += xv * nb.y; acc[14] += xv * nb.z; acc[15] += xv * nb.w;
  }
  __shared__ float red[4][16];
  int lane = tid & 63, wv = tid >> 6;
#pragma unroll
  for (int j = 0; j < 16; j++) {
    float v = acc[j];
    for (int o = 32; o > 0; o >>= 1) v += __shfl_down(v, o);
    acc[j] = v;
  }
  if (lane == 0) {
#pragma unroll
    for (int j = 0; j < 16; j++) red[wv][j] = acc[j];
  }
  __syncthreads();
  if (tid == 0) {
    float nz[EE];
#pragma unroll
    for (int e = 0; e < EE; e++) {
      float dg = red[0][e] + red[1][e] + red[2][e] + red[3][e] + bg[e];
      float dn = red[0][8 + e] + red[1][8 + e] + red[2][8 + e] + red[3][8 + e] + bn[e];
      float sp = fmaxf(dn, 0.f) + log1pf(expf(-fabsf(dn)));
      nz[e] = dg + noise[(size_t)t * EE + e] * sp;
    }
    int m1 = 0;
    for (int e = 1; e < EE; e++) if (nz[e] > nz[m1]) m1 = e;
    int m2 = (m1 == 0) ? 1 : 0;
    for (int e = 0; e < EE; e++) if (e != m1 && nz[e] > nz[m2]) m2 = e;
    float eb = expf(nz[m2] - nz[m1]);
    float den = 1.f + eb;
    float g1 = 1.f / den, g2 = eb / den;
#pragma unroll
    for (int e = 0; e < EE; e++)
      gating[(size_t)t * EE + e] = (e == m1) ? g1 : (e == m2) ? g2 : 0.f;
    sel_e[t * 2] = m1; sel_e[t * 2 + 1] = m2;
    sel_g[t * 2] = g1; sel_g[t * 2 + 1] = g2;
  }
}

// ---------------- histogram + scan + slot table (1 block); 256-row tiles
__global__ __launch_bounds__(256) void hist_scan_kernel(
    const int* __restrict__ sel_e, int* __restrict__ counts,
    int* __restrict__ offsets, int* __restrict__ cursors,
    int* __restrict__ slots) {
  __shared__ int hist[EE];
  int tid = threadIdx.x;
  if (tid < EE) hist[tid] = 0;
  __syncthreads();
  for (int i = tid; i < NASG; i += 256) atomicAdd(&hist[sel_e[i]], 1);
  __syncthreads();
  if (tid == 0) {
    int off = 0, ns = 0;
    for (int e = 0; e < EE; e++) {
      int c = hist[e];
      counts[e] = c; offsets[e] = off; cursors[e] = off; off += c;
      int nrt = (c + 255) >> 8;
      for (int rt = 0; rt < nrt; rt++) slots[ns++] = (e << 16) | rt;
    }
    for (; ns < NSLOT; ns++) slots[ns] = -1;
  }
}

// ---------------- build per-expert token lists (+ token->assignment-slot map)
__global__ __launch_bounds__(256) void build_lists_kernel(
    const int* __restrict__ sel_e, const float* __restrict__ sel_g,
    int* __restrict__ cursors, int* __restrict__ tok_list,
    float* __restrict__ gate_list, int* __restrict__ asg_of) {
  int t = blockIdx.x * 256 + threadIdx.x;
  int lane = threadIdx.x & 63;
#pragma unroll
  for (int k = 0; k < TOPK; k++) {
    int e = sel_e[t * 2 + k];
    float g = sel_g[t * 2 + k];
    for (int ee = 0; ee < EE; ee++) {
      unsigned long long m = __ballot(e == ee);
      if (m) {
        int leader = __ffsll(m) - 1;
        int base = 0;
        if (lane == leader) base = atomicAdd(&cursors[ee], __popcll(m));
        base = __shfl(base, leader);
        if (e == ee) {
          int slot = base + __popcll(m & ((1ull << lane) - 1ull));
          tok_list[slot] = t;
          gate_list[slot] = g;
          asg_of[t * 2 + k] = slot;
        }
      }
    }
  }
}

// ---------------- zero-fill non-selected expert_out rows (fallback path only)
__global__ __launch_bounds__(256) void zerofill_kernel(
    const float* __restrict__ gating, float* __restrict__ expert_out) {
  int id = blockIdx.x;              // 0 .. EE*TKN-1
  int e = id >> 13, t = id & (TKN - 1);
  if (gating[(size_t)t * EE + e] != 0.f) return;
  float4* p = (float4*)(expert_out + ((size_t)e * TKN + t) * DD);
  p[threadIdx.x] = (float4){0.f, 0.f, 0.f, 0.f};
}

// ---------------- combine (fallback path): final = expert rows sum
__global__ __launch_bounds__(256) void combine_kernel(
    const float* __restrict__ expert_out, const int* __restrict__ sel_e,
    float* __restrict__ final_out) {
  int t = blockIdx.x;
  int e1 = sel_e[2 * t], e2 = sel_e[2 * t + 1];
  const float4* r1 = (const float4*)(expert_out + ((size_t)e1 * TKN + t) * DD);
  const float4* r2 = (const float4*)(expert_out + ((size_t)e2 * TKN + t) * DD);
  float4* o = (float4*)(final_out + (size_t)t * DD);
  int i = threadIdx.x;
  float4 a = r1[i], b = r2[i];
  o[i] = (float4){a.x + b.x, a.y + b.y, a.z + b.z, a.w + b.w};
}

// ---------------- finalize: merge 4 bf16 K-partials + bias + gate, write ALL
// 8 expert rows per token (zeros for non-selected) + final.
__global__ __launch_bounds__(256) void finalize_kernel(
    const u16* __restrict__ part, const int* __restrict__ asg_of,
    const int* __restrict__ sel_e, const float* __restrict__ sel_g,
    const float* __restrict__ b2, float* __restrict__ expert_out,
    float* __restrict__ final_out) {
  int t = blockIdx.x;
  int i = threadIdx.x;
  int i1 = asg_of[2 * t], i2 = asg_of[2 * t + 1];
  int e1 = sel_e[2 * t], e2 = sel_e[2 * t + 1];
  float g1 = sel_g[2 * t], g2 = sel_g[2 * t + 1];
  float s1[4] = {0.f, 0.f, 0.f, 0.f}, s2[4] = {0.f, 0.f, 0.f, 0.f};
#pragma unroll
  for (int kq = 0; kq < 4; kq++) {
    ushort4 a = ((const ushort4*)(part + ((size_t)kq * NASG + i1) * DD))[i];
    ushort4 b = ((const ushort4*)(part + ((size_t)kq * NASG + i2) * DD))[i];
    s1[0] += bf2f(a.x); s1[1] += bf2f(a.y); s1[2] += bf2f(a.z); s1[3] += bf2f(a.w);
    s2[0] += bf2f(b.x); s2[1] += bf2f(b.y); s2[2] += bf2f(b.z); s2[3] += bf2f(b.w);
  }
  float4 bb1 = ((const float4*)(b2 + (size_t)e1 * DD))[i];
  float4 bb2 = ((const float4*)(b2 + (size_t)e2 * DD))[i];
  float4 y1 = {(s1[0] + bb1.x) * g1, (s1[1] + bb1.y) * g1,
               (s1[2] + bb1.z) * g1, (s1[3] + bb1.w) * g1};
  float4 y2 = {(s2[0] + bb2.x) * g2, (s2[1] + bb2.y) * g2,
               (s2[2] + bb2.z) * g2, (s2[3] + bb2.w) * g2};
  float4 z = {0.f, 0.f, 0.f, 0.f};
#pragma unroll
  for (int e = 0; e < EE; e++) {
    float4 v = (e == e1) ? y1 : (e == e2) ? y2 : z;
    ((float4*)(expert_out + ((size_t)e * TKN + t) * DD))[i] = v;
  }
  ((float4*)(final_out + (size_t)t * DD))[i] =
      (float4){y1.x + y2.x, y1.y + y2.y, y1.z + y2.z, y1.w + y2.w};
}

// ---------------- 256x256 / BK=64 / 8-wave grouped GEMM, 1-barrier-per-tile,
// interleaved aHi refill (round-10 core: best measured, 182-183 us/GEMM).
// Per K-tile: { issue glds(t+1); read aLo(8)+b(8); for mm=0..3 { 8 MFMA on
// aF[mm]; sched_barrier; refill aF[mm] <- aHi row; sched_barrier }; 32
// MFMA-hi; vmcnt(0); barrier }.
// WAR ledger: glds(t+1) writes parity (t+1)&1; its last readers R(t-1)
// drained per-wave before the tile-(t-1) barrier. RAW: reads of buf(t) gated
// by own vmcnt(0) (drains glds(t)) + barrier at end of tile t-1. Full drain
// each tile -> no counted-vmcnt races.
// LDS swizzle: stored 16B chunk c of row r holds global chunk c^(r&7) —
// linear glds dest + inverse-swizzled per-lane global source (involution).
// Decode (1-D grid, kq-outer within XCD): gid -> xcd=gid&7, q=gid>>3,
// kq=q/(9<<LOGC), r=q%(9<<LOGC), slot=xcd*9+(r>>LOGC), ct=r&mask.
// EPI: 0 = relu->bf16 OutBf; 1 = (acc+bias)*gate -> f32 outF; 2 = bf16
// K-partial -> outP[kq][asg][DD].
template<int KLOOP, int KSTRIDE, bool GATHER, int EPI, int LOGC>
__global__ __launch_bounds__(512, 2) void gemm8_kernel(
    const u16* __restrict__ A, const u16* __restrict__ Bm,
    const float* __restrict__ bias, const int* __restrict__ tok_list,
    const float* __restrict__ gate_list, const int* __restrict__ counts,
    const int* __restrict__ offsets, const int* __restrict__ slots,
    int Ncols, u16* __restrict__ OutBf, float* __restrict__ outF,
    u16* __restrict__ outP) {
  constexpr int NT = KLOOP / 64;
  int gid = blockIdx.x;
  int q = gid >> 3;
  constexpr int PERX = 9 << LOGC;
  int kq = q / PERX;
  int r0q = q - kq * PERX;
  int slot = (gid & 7) * 9 + (r0q >> LOGC);
  int ct = r0q & ((1 << LOGC) - 1);
  int packed = slots[slot];
  if (packed < 0) return;
  int e = packed >> 16;
  int rt = packed & 0xffff;
  int cnt = counts[e];
  int off = offsets[e];
  int col0 = ct * 256;
  int k0e = kq * KLOOP;   // element offset of this K-slice

  __shared__ __attribute__((aligned(16))) char ldsc[131072];  // A 64K | B 64K

  int tid = threadIdx.x;
  int w = tid >> 6, l = tid & 63;
  int wm = w >> 2, wn = w & 3;            // 2 x 4 wave grid
  int fr = l & 15, hi = l >> 4;
  int kk16 = hi << 4;
  int xr = (fr & 7) << 4;

  int rl0 = w * 8 + (l >> 3);
  int slotE = ((l & 7) ^ ((l >> 3) & 7)) << 3;  // pre-swizzled 8-elem slot
  const u16* aptr[4];
  const u16* bptr[4];
#pragma unroll
  for (int i = 0; i < 4; i++) {
    int r = rt * 256 + rl0 + i * 64;
    if (GATHER) {
      int idx = min(off + r, NASG - 1);
      aptr[i] = A + (size_t)tok_list[idx] * KSTRIDE + k0e + slotE;
    } else {
      aptr[i] = A + (size_t)(off + r) * KSTRIDE + k0e + slotE;
    }
    bptr[i] = Bm + ((size_t)e * Ncols + col0 + rl0 + i * 64) * KSTRIDE + k0e + slotE;
  }
  char* ldsA = ldsc;
  char* ldsB = ldsc + 65536;

  auto issueAB = [&](int t) {
    char* db = ldsB + (t & 1) * 32768 + w * 1024;
    char* da = ldsA + (t & 1) * 32768 + w * 1024;
    glds16(bptr[0] + t * 64, db);
    glds16(bptr[1] + t * 64, db + 8192);
    glds16(bptr[2] + t * 64, db + 16384);
    glds16(bptr[3] + t * 64, db + 24576);
    glds16(aptr[0] + t * 64, da);
    glds16(aptr[1] + t * 64, da + 8192);
    glds16(aptr[2] + t * 64, da + 16384);
    glds16(aptr[3] + t * 64, da + 24576);
  };

  f32x4 acc[8][4];
#pragma unroll
  for (int m = 0; m < 8; m++)
#pragma unroll
    for (int n = 0; n < 4; n++) acc[m][n] = (f32x4){0.f, 0.f, 0.f, 0.f};
  bf16x8 aF[4][2], bF0[2][2], bF1[2][2];

  // prologue: stage tile 0; drain; barrier
  issueAB(0);
  VMCNT0();
  BAR();

  for (int t = 0; t < NT; t++) {
    int abase = (t & 1) * 32768;
    int bbase = 65536 + (t & 1) * 32768;
    // depth-1 prefetch into parity (t+1)&1 (its last readers R(t-1) drained)
    if (t + 1 < NT) issueAB(t + 1);
    // read A-lo + all B fragments
#pragma unroll
    for (int mm = 0; mm < 4; mm++)
#pragma unroll
      for (int ks = 0; ks < 2; ks++)
        aF[mm][ks] = *(const bf16x8*)(ldsc + abase + (wm * 128 + mm * 16 + fr) * 128 +
                                      ((ks * 64 + kk16) ^ xr));
#pragma unroll
    for (int nn = 0; nn < 2; nn++)
#pragma unroll
      for (int ks = 0; ks < 2; ks++) {
        bF0[nn][ks] = *(const bf16x8*)(ldsc + bbase + (wn * 64 + nn * 16 + fr) * 128 +
                                       ((ks * 64 + kk16) ^ xr));
        bF1[nn][ks] = *(const bf16x8*)(ldsc + bbase + (wn * 64 + 32 + nn * 16 + fr) * 128 +
                                       ((ks * 64 + kk16) ^ xr));
      }
    __builtin_amdgcn_s_setprio(1);
    // MFMA-lo with per-group aHi refill: after the 8 MFMAs consuming aF[mm],
    // reload aF[mm] from the hi row; sched_barrier pins placement.
#pragma unroll
    for (int mm = 0; mm < 4; mm++) {
#pragma unroll
      for (int nn = 0; nn < 2; nn++)
#pragma unroll
        for (int ks = 0; ks < 2; ks++) {
          acc[mm][nn]     = __builtin_amdgcn_mfma_f32_16x16x32_bf16(aF[mm][ks], bF0[nn][ks], acc[mm][nn], 0, 0, 0);
          acc[mm][2 + nn] = __builtin_amdgcn_mfma_f32_16x16x32_bf16(aF[mm][ks], bF1[nn][ks], acc[mm][2 + nn], 0, 0, 0);
        }
      __builtin_amdgcn_sched_barrier(0);
#pragma unroll
      for (int ks = 0; ks < 2; ks++)
        aF[mm][ks] = *(const bf16x8*)(ldsc + abase + (wm * 128 + 64 + mm * 16 + fr) * 128 +
                                      ((ks * 64 + kk16) ^ xr));
      __builtin_amdgcn_sched_barrier(0);
    }
    // MFMA-hi (aF now holds hi rows; refills completed under MFMA-lo)
#pragma unroll
    for (int mm = 0; mm < 4; mm++)
#pragma unroll
      for (int nn = 0; nn < 2; nn++)
#pragma unroll
        for (int ks = 0; ks < 2; ks++) {
          acc[4 + mm][nn]     = __builtin_amdgcn_mfma_f32_16x16x32_bf16(aF[mm][ks], bF0[nn][ks], acc[4 + mm][nn], 0, 0, 0);
          acc[4 + mm][2 + nn] = __builtin_amdgcn_mfma_f32_16x16x32_bf16(aF[mm][ks], bF1[nn][ks], acc[4 + mm][2 + nn], 0, 0, 0);
        }
    __builtin_amdgcn_s_setprio(0);
    // drain own glds(t+1) (issued ~4000 cyc ago -> ~no stall) and sync
    VMCNT0();
    BAR();
  }

  // ---- epilogue
  float biasN[4];
  int cN[4];
#pragma unroll
  for (int n = 0; n < 4; n++) {
    cN[n] = col0 + wn * 64 + (n >> 1) * 32 + (n & 1) * 16 + fr;
    biasN[n] = (EPI == 2) ? 0.f : bias[e * Ncols + cN[n]];
  }
  if constexpr (EPI == 0) {
#pragma unroll
    for (int m = 0; m < 8; m++) {
      int rb = rt * 256 + wm * 128 + (m >> 2) * 64 + (m & 3) * 16 + hi * 4;
#pragma unroll
      for (int j = 0; j < 4; j++) {
        int r = rb + j;
        if (r < cnt) {
#pragma unroll
          for (int n = 0; n < 4; n++) {
            float v = acc[m][n][j] + biasN[n];
            OutBf[(size_t)(off + r) * Ncols + cN[n]] = f2bf(fmaxf(v, 0.f));
          }
        }
      }
    }
  } else if constexpr (EPI == 1) {
#pragma unroll
    for (int m = 0; m < 8; m++) {
      int rb = rt * 256 + wm * 128 + (m >> 2) * 64 + (m & 3) * 16 + hi * 4;
#pragma unroll
      for (int j = 0; j < 4; j++) {
        int r = rb + j;
        if (r < cnt) {
          int idx = off + r;
          int tok = tok_list[idx];
          float g = gate_list[idx];
          size_t erow = ((size_t)e * TKN + tok) * DD;
#pragma unroll
          for (int n = 0; n < 4; n++)
            outF[erow + cN[n]] = (acc[m][n][j] + biasN[n]) * g;
        }
      }
    }
  } else {
    // bf16 K-partial: outP[kq][asg][DD]
#pragma unroll
    for (int m = 0; m < 8; m++) {
      int rb = rt * 256 + wm * 128 + (m >> 2) * 64 + (m & 3) * 16 + hi * 4;
#pragma unroll
      for (int j = 0; j < 4; j++) {
        int r = rb + j;
        if (r < cnt) {
          size_t prow = ((size_t)kq * NASG + off + r) * DD;
#pragma unroll
          for (int n = 0; n < 4; n++)
            outP[prow + cN[n]] = f2bf(acc[m][n][j]);
        }
      }
    }
  }
}

extern "C" void kernel_launch(void* const* d_in, const int* in_sizes, int n_in,
                              void* d_out, int out_size, void* d_ws, size_t ws_size,
                              hipStream_t stream) {
  const float* x     = (const float*)d_in[0];
  const float* noise = (const float*)d_in[1];
  const float* Wg    = (const float*)d_in[2];
  const float* bg    = (const float*)d_in[3];
  const float* Wn    = (const float*)d_in[4];
  const float* bn    = (const float*)d_in[5];
  const float* W1    = (const float*)d_in[6];
  const float* b1    = (const float*)d_in[7];
  const float* W2    = (const float*)d_in[8];
  const float* b2    = (const float*)d_in[9];

  float* final_out  = (float*)d_out;
  float* expert_out = final_out + (size_t)TKN * DD;
  float* gating     = expert_out + (size_t)EE * TKN * DD;

  char* ws = (char*)d_ws;
  size_t o = 0;
  auto alloc = [&](size_t bytes) {
    char* p = ws + o;
    o += bytes;
    o = (o + 255) & ~(size_t)255;
    return p;
  };
  u16*   xb        = (u16*)alloc((size_t)TKN * DD * 2);
  u16*   w1t       = (u16*)alloc((size_t)EE * HH * DD * 2);        // [E][H][D]
  u16*   w2t       = (u16*)alloc((size_t)EE * DD * HH * 2);        // [E][D][H]
  u16*   hbuf      = (u16*)alloc(((size_t)NASG + 256) * HH * 2);   // +256 pad rows
  int*   tok_list  = (int*)alloc((size_t)NASG * 4);
  float* gate_list = (float*)alloc((size_t)NASG * 4);
  int*   sel_e     = (int*)alloc((size_t)NASG * 4);
  float* sel_g     = (float*)alloc((size_t)NASG * 4);
  int*   asg_of    = (int*)alloc((size_t)NASG * 4);
  int*   counts    = (int*)alloc(256);
  int*   offsets   = (int*)alloc(256);
  int*   cursors   = (int*)alloc(256);
  int*   slots     = (int*)alloc(NSLOT * 4);
  u16*   part      = (u16*)alloc((size_t)4 * NASG * DD * 2);       // 134 MB (last)
  bool use_split = (o <= ws_size);

  router_kernel<<<TKN, 256, 0, stream>>>(x, noise, Wg, bg, Wn, bn, gating, xb, sel_e, sel_g);
  hist_scan_kernel<<<1, 256, 0, stream>>>(sel_e, counts, offsets, cursors, slots);
  build_lists_kernel<<<TKN / 256, 256, 0, stream>>>(sel_e, sel_g, cursors, tok_list,
                                                    gate_list, asg_of);

  transpose_cvt_kernel<<<dim3(HH / 32, DD / 64, EE), dim3(32, 8), 0, stream>>>(W1, w1t, DD, HH);
  transpose_cvt_kernel<<<dim3(DD / 32, HH / 64, EE), dim3(32, 8), 0, stream>>>(W2, w2t, HH, DD);

  // GEMM1: h = relu(x[tok] @ W1[e] + b1), K=1024, N=4096; 16 col-tiles
  gemm8_kernel<DD, DD, true, 0, 4><<<8 * 9 * 16, 512, 0, stream>>>(
      xb, w1t, b1, tok_list, nullptr, counts, offsets, slots, HH, hbuf, nullptr, nullptr);

  if (use_split) {
    // GEMM2 split-K x4: bf16 partials, then fused finalize (merge + zeros + final)
    gemm8_kernel<HH / 4, HH, false, 2, 2><<<8 * 9 * 4 * 4, 512, 0, stream>>>(
        hbuf, w2t, b2, tok_list, gate_list, counts, offsets, slots, DD, nullptr, nullptr, part);
    finalize_kernel<<<TKN, 256, 0, stream>>>(part, asg_of, sel_e, sel_g, b2,
                                             expert_out, final_out);
  } else {
    // fallback: single-shot GEMM2 + zerofill + combine
    zerofill_kernel<<<EE * TKN, 256, 0, stream>>>(gating, expert_out);
    gemm8_kernel<HH, HH, false, 1, 2><<<8 * 9 * 4, 512, 0, stream>>>(
        hbuf, w2t, b2, tok_list, gate_list, counts, offsets, slots, DD, nullptr, expert_out, nullptr);
    combine_kernel<<<TKN, 256, 0, stream>>>(expert_out, sel_e, final_out);
  }
}